// Round 1
// baseline (209.380 us; speedup 1.0000x reference)
//
#include <hip/hip_runtime.h>

// Problem constants (from reference): H=1024, B=64, S=512.
// Math: out[b,:] = softmax_s( enc[b,s,:] . w2 ),  w2[k] = sum_h v[h]*W[h,2H+k].
// (hidden contribution is constant per row and bias is global -> both cancel
//  under softmax over s; folding v into W removes the [B,S,H] energy tensor.)

#define HID 1024
#define BB  64
#define SS  512
#define W3H 3072

// Kernel A: w2[k] = sum_h v[h] * W[h*3072 + 2048 + k].
// grid (4,16): blockIdx.x = k-chunk of 256, blockIdx.y = h-chunk of 64.
__global__ __launch_bounds__(256) void wfold_kernel(
        const float* __restrict__ W, const float* __restrict__ v,
        float* __restrict__ w2) {
    const int k  = blockIdx.x * 256 + threadIdx.x;
    const int h0 = blockIdx.y * 64;
    float acc = 0.0f;
    #pragma unroll 8
    for (int h = h0; h < h0 + 64; ++h)
        acc += v[h] * W[(size_t)h * W3H + 2 * HID + k];
    atomicAdd(&w2[k], acc);   // w2 zeroed by hipMemsetAsync before launch
}

// Kernel B: scores[r] = dot(enc[r,:], w2), one wave (64 lanes) per row,
// float4 loads: 64 lanes * 4 floats * 4 iters = 1024 elements.
__global__ __launch_bounds__(256) void scores_kernel(
        const float4* __restrict__ enc4, const float4* __restrict__ w24,
        float* __restrict__ scores) {
    const int wave = threadIdx.x >> 6;
    const int lane = threadIdx.x & 63;
    const int r = blockIdx.x * 4 + wave;            // r in [0, 32768)
    const float4* row = enc4 + (size_t)r * (HID / 4);
    float acc = 0.0f;
    #pragma unroll
    for (int i = 0; i < 4; ++i) {
        float4 e = row[i * 64 + lane];
        float4 w = w24[i * 64 + lane];
        acc += e.x * w.x + e.y * w.y + e.z * w.z + e.w * w.w;
    }
    #pragma unroll
    for (int off = 32; off > 0; off >>= 1)
        acc += __shfl_down(acc, off);
    if (lane == 0) scores[r] = acc;
}

// Kernel C: per-b softmax over 512 scores. One block of 512 threads per b.
__global__ __launch_bounds__(512) void softmax_kernel(
        const float* __restrict__ scores, float* __restrict__ out) {
    __shared__ float red[8];
    const int b = blockIdx.x;
    const int t = threadIdx.x;
    const int wave = t >> 6, lane = t & 63;

    float x = scores[b * SS + t];

    // block max
    float m = x;
    #pragma unroll
    for (int off = 32; off > 0; off >>= 1)
        m = fmaxf(m, __shfl_down(m, off));
    if (lane == 0) red[wave] = m;
    __syncthreads();
    if (t == 0) {
        float mm = red[0];
        #pragma unroll
        for (int i = 1; i < 8; ++i) mm = fmaxf(mm, red[i]);
        red[0] = mm;
    }
    __syncthreads();
    m = red[0];
    __syncthreads();                 // protect red before reuse

    float e = expf(x - m);

    // block sum
    float s = e;
    #pragma unroll
    for (int off = 32; off > 0; off >>= 1)
        s += __shfl_down(s, off);
    if (lane == 0) red[wave] = s;
    __syncthreads();
    if (t == 0) {
        float tot = 0.0f;
        #pragma unroll
        for (int i = 0; i < 8; ++i) tot += red[i];
        red[0] = tot;
    }
    __syncthreads();
    out[b * SS + t] = e / red[0];
}

extern "C" void kernel_launch(void* const* d_in, const int* in_sizes, int n_in,
                              void* d_out, int out_size, void* d_ws, size_t ws_size,
                              hipStream_t stream) {
    // inputs: hidden [2,64,1024] (unused), encoder_outputs [64,512,1024],
    //         W [1024,3072], b [1024] (unused), v [1024]
    const float* enc = (const float*)d_in[1];
    const float* W   = (const float*)d_in[2];
    const float* v   = (const float*)d_in[4];
    float* out = (float*)d_out;

    float* w2     = (float*)d_ws;         // 1024 floats
    float* scores = w2 + HID;             // 32768 floats

    hipMemsetAsync(w2, 0, HID * sizeof(float), stream);

    wfold_kernel<<<dim3(4, 16), 256, 0, stream>>>(W, v, w2);

    scores_kernel<<<(BB * SS) / 4, 256, 0, stream>>>(
        (const float4*)enc, (const float4*)w2, scores);

    softmax_kernel<<<BB, 512, 0, stream>>>(scores, out);
}

// Round 3
// 203.389 us; speedup vs baseline: 1.0295x; 1.0295x over previous
//
#include <hip/hip_runtime.h>

// Problem: out[b,:] = softmax_s( enc[b,s,:] . w2 ),  w2[k] = sum_h v[h]*W[h,2H+k].
// hidden/bias contributions are constant along s -> cancel under softmax(axis=1).
// HBM floor: read enc once = 64*512*1024*4 B = 134 MB (~21 us at 6.3 TB/s).

#define HID 1024
#define BB  64
#define SS  512
#define W3H 3072

// Native Clang ext-vector: accepted by __builtin_nontemporal_load (HIP's
// float4 struct is not).
typedef float floatx4 __attribute__((ext_vector_type(4)));

// Kernel A: w2[k] = sum_h v[h] * W[h*3072 + 2048 + k], no atomics/memset.
// grid 16 blocks x 1024 threads; thread = (hg = t>>6 in [0,16), kl = t&63);
// block x owns k in [64x, 64x+64); each thread sums 64 h-values, LDS-reduce.
__global__ __launch_bounds__(1024) void wfold_kernel(
        const float* __restrict__ W, const float* __restrict__ v,
        float* __restrict__ w2) {
    __shared__ float part[16][64];
    const int kl = threadIdx.x & 63;
    const int hg = threadIdx.x >> 6;            // 0..15
    const int k  = blockIdx.x * 64 + kl;
    float acc = 0.0f;
    #pragma unroll 8
    for (int h = hg * 64; h < hg * 64 + 64; ++h)
        acc += v[h] * W[(size_t)h * W3H + 2 * HID + k];
    part[hg][kl] = acc;
    __syncthreads();
    if (hg == 0) {
        float s = 0.0f;
        #pragma unroll
        for (int i = 0; i < 16; ++i) s += part[i][kl];
        w2[k] = s;
    }
}

// Kernel B: scores[r] = dot(enc[r,:], w2). One wave per row, 16B loads,
// nontemporal on enc (streamed once; keep caches for w2/scores).
__global__ __launch_bounds__(256) void scores_kernel(
        const floatx4* __restrict__ enc4, const floatx4* __restrict__ w24,
        float* __restrict__ scores) {
    const int wave = threadIdx.x >> 6;
    const int lane = threadIdx.x & 63;
    const int r = blockIdx.x * 4 + wave;            // r in [0, 32768)
    const floatx4* row = enc4 + (size_t)r * (HID / 4);
    float acc = 0.0f;
    #pragma unroll
    for (int i = 0; i < 4; ++i) {
        floatx4 e = __builtin_nontemporal_load(&row[i * 64 + lane]);
        floatx4 w = w24[i * 64 + lane];
        acc += e.x * w.x + e.y * w.y + e.z * w.z + e.w * w.w;
    }
    #pragma unroll
    for (int off = 32; off > 0; off >>= 1)
        acc += __shfl_down(acc, off);
    if (lane == 0) scores[r] = acc;
}

// Kernel C: per-b softmax over 512 scores. One block of 512 threads per b.
__global__ __launch_bounds__(512) void softmax_kernel(
        const float* __restrict__ scores, float* __restrict__ out) {
    __shared__ float red[8];
    const int b = blockIdx.x;
    const int t = threadIdx.x;
    const int wave = t >> 6, lane = t & 63;

    float x = scores[b * SS + t];

    float m = x;
    #pragma unroll
    for (int off = 32; off > 0; off >>= 1)
        m = fmaxf(m, __shfl_down(m, off));
    if (lane == 0) red[wave] = m;
    __syncthreads();
    if (t == 0) {
        float mm = red[0];
        #pragma unroll
        for (int i = 1; i < 8; ++i) mm = fmaxf(mm, red[i]);
        red[0] = mm;
    }
    __syncthreads();
    m = red[0];
    __syncthreads();

    float e = expf(x - m);

    float s = e;
    #pragma unroll
    for (int off = 32; off > 0; off >>= 1)
        s += __shfl_down(s, off);
    if (lane == 0) red[wave] = s;
    __syncthreads();
    if (t == 0) {
        float tot = 0.0f;
        #pragma unroll
        for (int i = 0; i < 8; ++i) tot += red[i];
        red[0] = tot;
    }
    __syncthreads();
    out[b * SS + t] = e / red[0];
}

extern "C" void kernel_launch(void* const* d_in, const int* in_sizes, int n_in,
                              void* d_out, int out_size, void* d_ws, size_t ws_size,
                              hipStream_t stream) {
    // inputs: hidden [2,64,1024] (unused), encoder_outputs [64,512,1024],
    //         W [1024,3072], b [1024] (unused), v [1024]
    const float* enc = (const float*)d_in[1];
    const float* W   = (const float*)d_in[2];
    const float* v   = (const float*)d_in[4];
    float* out = (float*)d_out;

    float* w2     = (float*)d_ws;         // 1024 floats
    float* scores = w2 + HID;             // 32768 floats

    wfold_kernel<<<16, 1024, 0, stream>>>(W, v, w2);

    scores_kernel<<<(BB * SS) / 4, 256, 0, stream>>>(
        (const floatx4*)enc, (const floatx4*)w2, scores);

    softmax_kernel<<<BB, 512, 0, stream>>>(scores, out);
}

// Round 4
// 199.036 us; speedup vs baseline: 1.0520x; 1.0219x over previous
//
#include <hip/hip_runtime.h>

// Problem: out[b,:] = softmax_s( enc[b,s,:] . w2 ),  w2[k] = sum_h v[h]*W[h,2H+k].
// hidden/bias contributions are constant along s -> cancel under softmax(axis=1).
// HBM floor: read enc once = 64*512*1024*4 B = 134 MB (~21 us at 6.3 TB/s).
// Measured dur_us also contains ~130-140 us of harness reset (536 MB ws poison
// fill + 147 MB input restore) visible as fillBufferAligned dispatches.

#define HID 1024
#define BB  64
#define SS  512
#define W3H 3072

// Native Clang ext-vector: accepted by __builtin_nontemporal_load (HIP's
// float4 struct is not).
typedef float floatx4 __attribute__((ext_vector_type(4)));

// Kernel A: w2[k] = sum_h v[h] * W[h*3072 + 2048 + k], no atomics/memset.
// 64 blocks x 1024 threads (was 16 blocks -> parallelism-starved, ~5-10 us).
// Block b owns k in [16b,16b+16); thread = (hg = t>>4 in [0,64), kl = t&15);
// each thread sums 16 h-values, then LDS-reduce over the 64 h-groups.
__global__ __launch_bounds__(1024) void wfold_kernel(
        const float* __restrict__ W, const float* __restrict__ v,
        float* __restrict__ w2) {
    __shared__ float part[64][16];
    const int kl = threadIdx.x & 15;
    const int hg = threadIdx.x >> 4;            // 0..63
    const int k  = blockIdx.x * 16 + kl;
    float acc = 0.0f;
    #pragma unroll
    for (int h = hg * 16; h < hg * 16 + 16; ++h)
        acc += v[h] * W[(size_t)h * W3H + 2 * HID + k];
    part[hg][kl] = acc;
    __syncthreads();
    // tree-reduce over hg: 64 -> 32 -> ... -> 1
    for (int half = 32; half >= 1; half >>= 1) {
        if (hg < half) part[hg][kl] += part[hg + half][kl];
        __syncthreads();
    }
    if (threadIdx.x < 16) w2[k] = part[0][kl];
}

// Kernel B: scores[r] = dot(enc[r,:], w2). One wave per row, 16B loads,
// nontemporal on enc (streamed once; keep caches for w2/scores).
__global__ __launch_bounds__(256) void scores_kernel(
        const floatx4* __restrict__ enc4, const floatx4* __restrict__ w24,
        float* __restrict__ scores) {
    const int wave = threadIdx.x >> 6;
    const int lane = threadIdx.x & 63;
    const int r = blockIdx.x * 4 + wave;            // r in [0, 32768)
    const floatx4* row = enc4 + (size_t)r * (HID / 4);
    float acc = 0.0f;
    #pragma unroll
    for (int i = 0; i < 4; ++i) {
        floatx4 e = __builtin_nontemporal_load(&row[i * 64 + lane]);
        floatx4 w = w24[i * 64 + lane];
        acc += e.x * w.x + e.y * w.y + e.z * w.z + e.w * w.w;
    }
    #pragma unroll
    for (int off = 32; off > 0; off >>= 1)
        acc += __shfl_down(acc, off);
    if (lane == 0) scores[r] = acc;
}

// Kernel C: per-b softmax over 512 scores. One block of 512 threads per b.
__global__ __launch_bounds__(512) void softmax_kernel(
        const float* __restrict__ scores, float* __restrict__ out) {
    __shared__ float red[8];
    const int b = blockIdx.x;
    const int t = threadIdx.x;
    const int wave = t >> 6, lane = t & 63;

    float x = scores[b * SS + t];

    float m = x;
    #pragma unroll
    for (int off = 32; off > 0; off >>= 1)
        m = fmaxf(m, __shfl_down(m, off));
    if (lane == 0) red[wave] = m;
    __syncthreads();
    if (t == 0) {
        float mm = red[0];
        #pragma unroll
        for (int i = 1; i < 8; ++i) mm = fmaxf(mm, red[i]);
        red[0] = mm;
    }
    __syncthreads();
    m = red[0];
    __syncthreads();

    float e = expf(x - m);

    float s = e;
    #pragma unroll
    for (int off = 32; off > 0; off >>= 1)
        s += __shfl_down(s, off);
    if (lane == 0) red[wave] = s;
    __syncthreads();
    if (t == 0) {
        float tot = 0.0f;
        #pragma unroll
        for (int i = 0; i < 8; ++i) tot += red[i];
        red[0] = tot;
    }
    __syncthreads();
    out[b * SS + t] = e / red[0];
}

extern "C" void kernel_launch(void* const* d_in, const int* in_sizes, int n_in,
                              void* d_out, int out_size, void* d_ws, size_t ws_size,
                              hipStream_t stream) {
    // inputs: hidden [2,64,1024] (unused), encoder_outputs [64,512,1024],
    //         W [1024,3072], b [1024] (unused), v [1024]
    const float* enc = (const float*)d_in[1];
    const float* W   = (const float*)d_in[2];
    const float* v   = (const float*)d_in[4];
    float* out = (float*)d_out;

    float* w2     = (float*)d_ws;         // 1024 floats
    float* scores = w2 + HID;             // 32768 floats

    wfold_kernel<<<64, 1024, 0, stream>>>(W, v, w2);

    scores_kernel<<<(BB * SS) / 4, 256, 0, stream>>>(
        (const floatx4*)enc, (const floatx4*)w2, scores);

    softmax_kernel<<<BB, 512, 0, stream>>>(scores, out);
}